// Round 5
// baseline (144.366 us; speedup 1.0000x reference)
//
#include <hip/hip_runtime.h>
#include <hip/hip_bf16.h>
#include <stdint.h>

#define S_LEN 2048
#define NB 2
#define NH 16
#define DK 64
#define DM 1024
#define QK_SCALE 0.125f
#define NEG_BIG -1e30f

typedef __attribute__((ext_vector_type(8))) short bf16x8;
typedef __attribute__((ext_vector_type(4))) float f32x4;

static __device__ __forceinline__ f32x4 mfma16(bf16x8 a, bf16x8 b, f32x4 c) {
    return __builtin_amdgcn_mfma_f32_16x16x32_bf16(a, b, c, 0, 0, 0);
}

// async global->LDS, 16B per lane; dst is wave-uniform base, HW adds lane*16
static __device__ __forceinline__ void gload_lds16(const void* g, void* l) {
    __builtin_amdgcn_global_load_lds((const __attribute__((address_space(1))) void*)g,
                                     (__attribute__((address_space(3))) void*)l,
                                     16, 0, 0);
}

// fp32 -> bf16 bits, RNE (inputs always finite here)
static __device__ __forceinline__ unsigned short f2bf(float x) {
    unsigned int u = __float_as_uint(x);
    u += 0x7fffu + ((u >> 16) & 1u);
    return (unsigned short)(u >> 16);
}

// packed pair fp32 -> 2x bf16 (RNE; hardware v_cvt_pk_bf16_f32 via header)
static __device__ __forceinline__ unsigned int pkbf(float lo, float hi) {
    __hip_bfloat162 h = __float22bfloat162_rn(make_float2(lo, hi));
    union { __hip_bfloat162 h2; unsigned int w; } u;
    u.h2 = h;
    return u.w;
}

// ---------------- conversion: fp32 -> bf16, WEIGHTS ONLY (4 tensors) ------
struct CvtArgs {
    const float* src[4];
    unsigned short* dst[4];
};

__global__ __launch_bounds__(256) void cvt_f32_bf16(CvtArgs a) {
    const int t = blockIdx.y;
    const float* __restrict__ src = a.src[t];
    unsigned short* __restrict__ dst = a.dst[t];
    const int i = blockIdx.x * blockDim.x + threadIdx.x;   // exactly covers DM*DM/8
    float4 v0 = ((const float4*)src)[(size_t)i * 2];
    float4 v1 = ((const float4*)src)[(size_t)i * 2 + 1];
    union { bf16x8 v; unsigned int w[4]; } u;
    u.w[0] = pkbf(v0.x, v0.y); u.w[1] = pkbf(v0.z, v0.w);
    u.w[2] = pkbf(v1.x, v1.y); u.w[3] = pkbf(v1.z, v1.w);
    ((bf16x8*)dst)[i] = u.v;
}

// ---------------- merged QKV projection, fp32-A fused conversion -----------
// Round-1 m97 structure (128^2 tile, BK=64, 2 barriers/K-step, 768 blocks).
// A (= q/k/v input, fp32) is reg-staged: 8x float4 load -> 16 cvt_pk ->
// 4x swizzled ds_write_b128 (cg ^= row&7, both write and frag-read sides).
// B (= weights, bf16) stays global_load_lds with linear LDS.
// z=0: Q -> [B,H,S,dk]; z=1: K -> [B,H,S,dk]; z=2: V -> [B,H,dk,S].
__global__ __launch_bounds__(256, 2) void gemm_qkv(
    const float* __restrict__ Xq, const float* __restrict__ Xk,
    const float* __restrict__ Xv,
    const unsigned short* __restrict__ Wq, const unsigned short* __restrict__ Wk,
    const unsigned short* __restrict__ Wv,
    const float* __restrict__ bq, const float* __restrict__ bk, const float* __restrict__ bv,
    unsigned short* __restrict__ Qo, unsigned short* __restrict__ Ko,
    unsigned short* __restrict__ Vt)
{
    __shared__ unsigned short sA[128 * 64];
    __shared__ unsigned short sB[128 * 64];

    const int tid = threadIdx.x;
    const int wid = tid >> 6, lane = tid & 63;
    const int wr = wid >> 1, wc = wid & 1;
    const int fr = lane & 15, fg = lane >> 4;
    const int z = blockIdx.z;
    const int m0 = blockIdx.y * 128, n0 = blockIdx.x * 128;

    const float* A = (z == 0) ? Xq : ((z == 1) ? Xk : Xv);
    const unsigned short* W = (z == 0) ? Wq : ((z == 1) ? Wk : Wv);
    const float* bias = (z == 0) ? bq : ((z == 1) ? bk : bv);

    // B staging (global_load_lds, per round-1)
    const int ldr = lane >> 3, ldc = (lane & 7) * 8;
    const unsigned short* pW = W + (size_t)(n0 + ldr) * DM + ldc;

    // A reg-stage mapping: thread t covers row t>>1, colgroups acg0..acg0+3
    const int arow = tid >> 1;
    const int acg0 = (tid & 1) * 4;
    const float* pA = A + (size_t)(m0 + arow) * DM + acg0 * 8;

    // frag-read swizzled chunk offsets (row&7 == fr&7 for all A fragments)
    const int cka0 = ((0 + fg) ^ (fr & 7)) * 8;
    const int cka1 = ((4 + fg) ^ (fr & 7)) * 8;

    f32x4 acc[4][4] = {};

    for (int k0 = 0; k0 < DM; k0 += 64) {
        __syncthreads();  // previous compute done reading LDS
        // B: 4 gload_lds per wave (16KB tile)
        #pragma unroll
        for (int it = 0; it < 4; ++it) {
            const int rb = wid * 32 + it * 8;
            gload_lds16(pW + (size_t)rb * DM + k0, sB + rb * 64);
        }
        // A: fp32 global -> regs -> bf16 -> swizzled LDS
        {
            const float* ga = pA + k0;
            float4 f0 = *(const float4*)(ga + 0);
            float4 f1 = *(const float4*)(ga + 4);
            float4 f2 = *(const float4*)(ga + 8);
            float4 f3 = *(const float4*)(ga + 12);
            float4 f4 = *(const float4*)(ga + 16);
            float4 f5 = *(const float4*)(ga + 20);
            float4 f6 = *(const float4*)(ga + 24);
            float4 f7 = *(const float4*)(ga + 28);
            union { bf16x8 v; unsigned int w[4]; } u;
            unsigned short* sArow = sA + arow * 64;
            const int rsw = arow & 7;
            u.w[0] = pkbf(f0.x, f0.y); u.w[1] = pkbf(f0.z, f0.w);
            u.w[2] = pkbf(f1.x, f1.y); u.w[3] = pkbf(f1.z, f1.w);
            *(bf16x8*)(sArow + ((acg0 + 0) ^ rsw) * 8) = u.v;
            u.w[0] = pkbf(f2.x, f2.y); u.w[1] = pkbf(f2.z, f2.w);
            u.w[2] = pkbf(f3.x, f3.y); u.w[3] = pkbf(f3.z, f3.w);
            *(bf16x8*)(sArow + ((acg0 + 1) ^ rsw) * 8) = u.v;
            u.w[0] = pkbf(f4.x, f4.y); u.w[1] = pkbf(f4.z, f4.w);
            u.w[2] = pkbf(f5.x, f5.y); u.w[3] = pkbf(f5.z, f5.w);
            *(bf16x8*)(sArow + ((acg0 + 2) ^ rsw) * 8) = u.v;
            u.w[0] = pkbf(f6.x, f6.y); u.w[1] = pkbf(f6.z, f6.w);
            u.w[2] = pkbf(f7.x, f7.y); u.w[3] = pkbf(f7.z, f7.w);
            *(bf16x8*)(sArow + ((acg0 + 3) ^ rsw) * 8) = u.v;
        }
        __syncthreads();  // staged data (vmcnt + lgkm) visible

        #pragma unroll
        for (int kf = 0; kf < 2; ++kf) {
            bf16x8 af[4], bfr[4];
            const int cka = kf ? cka1 : cka0;
            #pragma unroll
            for (int mf = 0; mf < 4; ++mf)
                af[mf] = *(const bf16x8*)(sA + (wr * 64 + mf * 16 + fr) * 64 + cka);
            #pragma unroll
            for (int nf = 0; nf < 4; ++nf)
                bfr[nf] = *(const bf16x8*)(sB + (wc * 64 + nf * 16 + fr) * 64 + kf * 32 + fg * 8);
            #pragma unroll
            for (int mf = 0; mf < 4; ++mf)
                #pragma unroll
                for (int nf = 0; nf < 4; ++nf)
                    acc[mf][nf] = mfma16(af[mf], bfr[nf], acc[mf][nf]);
        }
    }

    // epilogue (identical to round 1)
    unsigned short* Oh = (z == 0) ? Qo : Ko;
    #pragma unroll
    for (int nf = 0; nf < 4; ++nf) {
        const int col = n0 + wc * 64 + nf * 16 + fr;
        const float bb = bias[col];
        const int h = col >> 6, dd = col & (DK - 1);
        #pragma unroll
        for (int mf = 0; mf < 4; ++mf) {
            #pragma unroll
            for (int r = 0; r < 4; ++r) {
                const int row = m0 + wr * 64 + mf * 16 + fg * 4 + r;
                const int b = row >> 11, s = row & (S_LEN - 1);
                const float val = acc[mf][nf][r] + bb;
                if (z < 2)
                    Oh[(((size_t)b * NH + h) * S_LEN + s) * DK + dd] = f2bf(val);
                else
                    Vt[(((size_t)b * NH + h) * DK + dd) * S_LEN + s] = f2bf(val);
            }
        }
    }
}

// ---------------- GEMM core (m97 128^2) for the output projection ----------
static __device__ __forceinline__ void gemm_core_128(
    const unsigned short* __restrict__ A,
    const unsigned short* __restrict__ W,
    unsigned short* sA, unsigned short* sB,
    int K, int m0, int n0, f32x4 acc[4][4])
{
    const int tid = threadIdx.x;
    const int wid = tid >> 6, lane = tid & 63;
    const int wr = wid >> 1, wc = wid & 1;
    const int fr = lane & 15, fg = lane >> 4;
    const int ldr = lane >> 3, ldc = (lane & 7) * 8;

    const unsigned short* pA = A + (size_t)(m0 + ldr) * K + ldc;
    const unsigned short* pW = W + (size_t)(n0 + ldr) * K + ldc;

    for (int k0 = 0; k0 < K; k0 += 64) {
        __syncthreads();
        #pragma unroll
        for (int it = 0; it < 4; ++it) {
            const int rb = wid * 32 + it * 8;
            gload_lds16(pA + (size_t)(rb)*K + k0, sA + rb * 64);
            gload_lds16(pW + (size_t)(rb)*K + k0, sB + rb * 64);
        }
        __syncthreads();
        #pragma unroll
        for (int kf = 0; kf < 2; ++kf) {
            bf16x8 af[4], bfr[4];
            #pragma unroll
            for (int mf = 0; mf < 4; ++mf)
                af[mf] = *(const bf16x8*)(sA + (wr * 64 + mf * 16 + fr) * 64 + kf * 32 + fg * 8);
            #pragma unroll
            for (int nf = 0; nf < 4; ++nf)
                bfr[nf] = *(const bf16x8*)(sB + (wc * 64 + nf * 16 + fr) * 64 + kf * 32 + fg * 8);
            #pragma unroll
            for (int mf = 0; mf < 4; ++mf)
                #pragma unroll
                for (int nf = 0; nf < 4; ++nf)
                    acc[mf][nf] = mfma16(af[mf], bfr[nf], acc[mf][nf]);
        }
    }
}

// ---------------- final output projection: fp32 out + bias -----------------
__global__ __launch_bounds__(256, 2) void gemm_out(
    const unsigned short* __restrict__ A, const unsigned short* __restrict__ W,
    const float* __restrict__ bias, float* __restrict__ out)
{
    __shared__ unsigned short sA[128 * 64];
    __shared__ unsigned short sB[128 * 64];
    const int m0 = blockIdx.y * 128, n0 = blockIdx.x * 128;
    f32x4 acc[4][4] = {};
    gemm_core_128(A, W, sA, sB, DM, m0, n0, acc);
    const int tid = threadIdx.x, wid = tid >> 6, lane = tid & 63;
    const int wr = wid >> 1, wc = wid & 1, fr = lane & 15, fg = lane >> 4;
    #pragma unroll
    for (int nf = 0; nf < 4; ++nf) {
        const int col = n0 + wc * 64 + nf * 16 + fr;
        const float bb = bias[col];
        #pragma unroll
        for (int mf = 0; mf < 4; ++mf) {
            #pragma unroll
            for (int r = 0; r < 4; ++r) {
                const int row = m0 + wr * 64 + mf * 16 + fg * 4 + r;
                out[(size_t)row * DM + col] = acc[mf][nf][r] + bb;
            }
        }
    }
}

// ---------------- banded flash attention ----------------------------------
__global__ __launch_bounds__(256, 2) void attn_kernel(
    const unsigned short* __restrict__ Qb,   // [B,H,S,64]
    const unsigned short* __restrict__ Kb,   // [B,H,S,64]
    const unsigned short* __restrict__ Vt,   // [B,H,64,S]
    unsigned short* __restrict__ Oout)       // [B*S, 1024] token-major
{
    __shared__ unsigned short sK[128 * 64];
    __shared__ unsigned short sV[64 * 128];
    __shared__ unsigned short sP[4][32 * 128];

    const int tid = threadIdx.x, wid = tid >> 6, lane = tid & 63;
    const int fr = lane & 15, fg = lane >> 4;
    const int qt = blockIdx.x, bh = blockIdx.y;
    const int q0 = qt * 128;
    const size_t base = (size_t)bh * (S_LEN * DK);

    bf16x8 qf[2][2];
    #pragma unroll
    for (int mf = 0; mf < 2; ++mf)
        #pragma unroll
        for (int kf = 0; kf < 2; ++kf)
            qf[mf][kf] = *(const bf16x8*)(Qb + base +
                (size_t)(q0 + wid * 32 + mf * 16 + fr) * DK + kf * 32 + fg * 8);

    f32x4 oacc[2][4] = {};
    float m_run[2][4], l_run[2][4];
    #pragma unroll
    for (int mf = 0; mf < 2; ++mf)
        #pragma unroll
        for (int r = 0; r < 4; ++r) { m_run[mf][r] = NEG_BIG; l_run[mf][r] = 0.f; }

    const int t_lo = (qt == 0) ? 1 : 0;
    const int t_hi = (qt == (S_LEN / 128 - 1)) ? 1 : 2;

    for (int t = t_lo; t <= t_hi; ++t) {
        const int kt0 = q0 + (t - 1) * 128;
        __syncthreads();
        {
            const unsigned short* gK = Kb + base + (size_t)kt0 * DK;
            #pragma unroll
            for (int it = 0; it < 4; ++it) {
                const int chunk = wid * 4 + it;
                gload_lds16(gK + chunk * 512 + lane * 8, sK + chunk * 512);
            }
            const unsigned short* gV = Vt + base + kt0;
            #pragma unroll
            for (int it = 0; it < 4; ++it) {
                const int chunk = wid * 4 + it;
                gload_lds16(gV + (size_t)(chunk * 4 + fg) * S_LEN + fr * 8, sV + chunk * 512);
            }
        }
        __syncthreads();

        f32x4 sacc[2][8] = {};
        #pragma unroll
        for (int kf = 0; kf < 2; ++kf) {
            bf16x8 kfr[8];
            #pragma unroll
            for (int nf = 0; nf < 8; ++nf)
                kfr[nf] = *(const bf16x8*)(sK + (nf * 16 + fr) * 64 + kf * 32 + fg * 8);
            #pragma unroll
            for (int mf = 0; mf < 2; ++mf)
                #pragma unroll
                for (int nf = 0; nf < 8; ++nf)
                    sacc[mf][nf] = mfma16(qf[mf][kf], kfr[nf], sacc[mf][nf]);
        }

        const int dt = (t - 1) * 128;
        #pragma unroll
        for (int mf = 0; mf < 2; ++mf) {
            #pragma unroll
            for (int r = 0; r < 4; ++r) {
                const int row = wid * 32 + mf * 16 + fg * 4 + r;
                float mm = NEG_BIG;
                #pragma unroll
                for (int nf = 0; nf < 8; ++nf) {
                    const int col = nf * 16 + fr;
                    const int diff = dt + col - row;
                    float s = sacc[mf][nf][r] * QK_SCALE;
                    s = (diff >= -128 && diff < 128) ? s : NEG_BIG;
                    sacc[mf][nf][r] = s;
                    mm = fmaxf(mm, s);
                }
                #pragma unroll
                for (int d = 1; d < 16; d <<= 1) mm = fmaxf(mm, __shfl_xor(mm, d));
                const float mold = m_run[mf][r];
                const float mn = fmaxf(mold, mm);
                m_run[mf][r] = mn;
                const float alpha = __expf(mold - mn);
                float ps = 0.f;
                #pragma unroll
                for (int nf = 0; nf < 8; ++nf) {
                    const float p = __expf(sacc[mf][nf][r] - mn);
                    ps += p;
                    sP[wid][(mf * 16 + fg * 4 + r) * 128 + nf * 16 + fr] = f2bf(p);
                }
                #pragma unroll
                for (int d = 1; d < 16; d <<= 1) ps += __shfl_xor(ps, d);
                l_run[mf][r] = l_run[mf][r] * alpha + ps;
                #pragma unroll
                for (int nf = 0; nf < 4; ++nf)
                    oacc[mf][nf][r] = oacc[mf][nf][r] * alpha;
            }
        }

        #pragma unroll
        for (int kf = 0; kf < 4; ++kf) {
            bf16x8 pa[2], vb[4];
            #pragma unroll
            for (int mf = 0; mf < 2; ++mf)
                pa[mf] = *(const bf16x8*)(&sP[wid][(mf * 16 + fr) * 128 + kf * 32 + fg * 8]);
            #pragma unroll
            for (int nf = 0; nf < 4; ++nf)
                vb[nf] = *(const bf16x8*)(sV + (nf * 16 + fr) * 128 + kf * 32 + fg * 8);
            #pragma unroll
            for (int mf = 0; mf < 2; ++mf)
                #pragma unroll
                for (int nf = 0; nf < 4; ++nf)
                    oacc[mf][nf] = mfma16(pa[mf], vb[nf], oacc[mf][nf]);
        }
    }

    const int b = bh >> 4, h = bh & 15;
    #pragma unroll
    for (int mf = 0; mf < 2; ++mf) {
        #pragma unroll
        for (int r = 0; r < 4; ++r) {
            const float inv = 1.0f / l_run[mf][r];
            const int token = b * S_LEN + q0 + wid * 32 + mf * 16 + fg * 4 + r;
            #pragma unroll
            for (int nf = 0; nf < 4; ++nf) {
                const int feat = h * 64 + nf * 16 + fr;
                Oout[(size_t)token * DM + feat] = f2bf(oacc[mf][nf][r] * inv);
            }
        }
    }
}

// ---------------------------------------------------------------------------
extern "C" void kernel_launch(void* const* d_in, const int* in_sizes, int n_in,
                              void* d_out, int out_size, void* d_ws, size_t ws_size,
                              hipStream_t stream)
{
    (void)in_sizes; (void)n_in; (void)out_size; (void)ws_size;
    const float* q  = (const float*)d_in[0];
    const float* k  = (const float*)d_in[1];
    const float* v  = (const float*)d_in[2];
    const float* Wq = (const float*)d_in[3];
    const float* bq = (const float*)d_in[4];
    const float* Wk = (const float*)d_in[5];
    const float* bk = (const float*)d_in[6];
    const float* Wv = (const float*)d_in[7];
    const float* bv = (const float*)d_in[8];
    const float* Wo = (const float*)d_in[9];
    const float* bo = (const float*)d_in[10];

    char* ws = (char*)d_ws;
    const size_t MB = 1024 * 1024;
    unsigned short* AO  = (unsigned short*)(ws + 0 * MB);   // attn out, 8 MiB
    unsigned short* Qb  = (unsigned short*)(ws + 8 * MB);   // 8 MiB
    unsigned short* Kb  = (unsigned short*)(ws + 16 * MB);  // 8 MiB
    unsigned short* Vt  = (unsigned short*)(ws + 24 * MB);  // 8 MiB
    unsigned short* Wqb = (unsigned short*)(ws + 32 * MB);  // 2 MiB
    unsigned short* Wkb = (unsigned short*)(ws + 34 * MB);  // 2 MiB
    unsigned short* Wvb = (unsigned short*)(ws + 36 * MB);  // 2 MiB
    unsigned short* Wob = (unsigned short*)(ws + 38 * MB);  // 2 MiB

    CvtArgs ca;
    ca.src[0] = Wq; ca.dst[0] = Wqb;
    ca.src[1] = Wk; ca.dst[1] = Wkb;
    ca.src[2] = Wv; ca.dst[2] = Wvb;
    ca.src[3] = Wo; ca.dst[3] = Wob;
    cvt_f32_bf16<<<dim3((DM * DM / 8) / 256, 4), 256, 0, stream>>>(ca);

    gemm_qkv<<<dim3(DM / 128, (NB * S_LEN) / 128, 3), 256, 0, stream>>>(
        q, k, v, Wqb, Wkb, Wvb, bq, bk, bv, Qb, Kb, Vt);

    attn_kernel<<<dim3(S_LEN / 128, NB * NH), 256, 0, stream>>>(Qb, Kb, Vt, AO);

    gemm_out<<<dim3(DM / 128, (NB * S_LEN) / 128), 256, 0, stream>>>(
        AO, Wob, bo, (float*)d_out);
}

// Round 6
// 113.127 us; speedup vs baseline: 1.2761x; 1.2761x over previous
//
#include <hip/hip_runtime.h>
#include <stdint.h>

#define S_LEN 2048
#define NB 2
#define NH 16
#define DK 64
#define DM 1024
#define QK_SCALE 0.125f
#define NEG_BIG -1e30f

typedef __attribute__((ext_vector_type(8))) short bf16x8;
typedef __attribute__((ext_vector_type(4))) float f32x4;

static __device__ __forceinline__ f32x4 mfma16(bf16x8 a, bf16x8 b, f32x4 c) {
    return __builtin_amdgcn_mfma_f32_16x16x32_bf16(a, b, c, 0, 0, 0);
}

// async global->LDS, 16B per lane; dst is wave-uniform base, HW adds lane*16
static __device__ __forceinline__ void gload_lds16(const void* g, void* l) {
    __builtin_amdgcn_global_load_lds((const __attribute__((address_space(1))) void*)g,
                                     (__attribute__((address_space(3))) void*)l,
                                     16, 0, 0);
}

// fp32 -> bf16 bits, RNE (inputs always finite here)
static __device__ __forceinline__ unsigned short f2bf(float x) {
    unsigned int u = __float_as_uint(x);
    u += 0x7fffu + ((u >> 16) & 1u);
    return (unsigned short)(u >> 16);
}

// ---------------- conversion: fp32 -> bf16, 7 tensors in one launch -------
struct CvtArgs {
    const float* src[7];
    unsigned short* dst[7];
    int n8[7];
};

__global__ __launch_bounds__(256) void cvt_f32_bf16(CvtArgs a) {
    const int t = blockIdx.y;
    const float* __restrict__ src = a.src[t];
    unsigned short* __restrict__ dst = a.dst[t];
    const int n8 = a.n8[t];
    const int stride = gridDim.x * blockDim.x;
    for (int i = blockIdx.x * blockDim.x + threadIdx.x; i < n8; i += stride) {
        float4 v0 = ((const float4*)src)[(size_t)i * 2];
        float4 v1 = ((const float4*)src)[(size_t)i * 2 + 1];
        union { bf16x8 v; unsigned short h[8]; } u;
        u.h[0] = f2bf(v0.x); u.h[1] = f2bf(v0.y); u.h[2] = f2bf(v0.z); u.h[3] = f2bf(v0.w);
        u.h[4] = f2bf(v1.x); u.h[5] = f2bf(v1.y); u.h[6] = f2bf(v1.z); u.h[7] = f2bf(v1.w);
        ((bf16x8*)dst)[i] = u.v;
    }
}

// ---------------- GEMM core: C[128x128] = A[M,K] * W[N,K]^T ----------------
// m97-structure: 128^2 tile, BK=64, global_load_lds(16B), 2 barriers/K-step.
// 4 waves, each computes a 64x64 quadrant as 4x4 16x16x32 fragments.
static __device__ __forceinline__ void gemm_core_128(
    const unsigned short* __restrict__ A,
    const unsigned short* __restrict__ W,
    unsigned short* sA, unsigned short* sB,
    int K, int m0, int n0, f32x4 acc[4][4])
{
    const int tid = threadIdx.x;
    const int wid = tid >> 6, lane = tid & 63;
    const int wr = wid >> 1, wc = wid & 1;
    const int fr = lane & 15, fg = lane >> 4;
    const int ldr = lane >> 3, ldc = (lane & 7) * 8;

    const unsigned short* pA = A + (size_t)(m0 + ldr) * K + ldc;
    const unsigned short* pW = W + (size_t)(n0 + ldr) * K + ldc;

    for (int k0 = 0; k0 < K; k0 += 64) {
        __syncthreads();  // previous compute done reading LDS
        #pragma unroll
        for (int it = 0; it < 4; ++it) {
            const int rb = wid * 32 + it * 8;   // 8 rows per call (64 lanes * 16B)
            gload_lds16(pA + (size_t)(rb)*K + k0, sA + rb * 64);
            gload_lds16(pW + (size_t)(rb)*K + k0, sB + rb * 64);
        }
        __syncthreads();  // implies s_waitcnt vmcnt(0): staged data visible
        #pragma unroll
        for (int kf = 0; kf < 2; ++kf) {
            bf16x8 af[4], bfr[4];
            #pragma unroll
            for (int mf = 0; mf < 4; ++mf)
                af[mf] = *(const bf16x8*)(sA + (wr * 64 + mf * 16 + fr) * 64 + kf * 32 + fg * 8);
            #pragma unroll
            for (int nf = 0; nf < 4; ++nf)
                bfr[nf] = *(const bf16x8*)(sB + (wc * 64 + nf * 16 + fr) * 64 + kf * 32 + fg * 8);
            #pragma unroll
            for (int mf = 0; mf < 4; ++mf)
                #pragma unroll
                for (int nf = 0; nf < 4; ++nf)
                    acc[mf][nf] = mfma16(af[mf], bfr[nf], acc[mf][nf]);
        }
    }
}

// ---------------- merged QKV projection (grid.z selects Q/K/V) -------------
// z=0: Q -> [B,H,S,dk]; z=1: K -> [B,H,S,dk]; z=2: V -> [B,H,dk,S] (transposed)
// launch_bounds(256,3): 768 blocks all co-resident (3 blocks/CU) — no tail
// round, and 3-way cross-block overlap hides the per-K-step barrier drain.
__global__ __launch_bounds__(256, 3) void gemm_qkv(
    const unsigned short* __restrict__ Xq, const unsigned short* __restrict__ Xk,
    const unsigned short* __restrict__ Xv,
    const unsigned short* __restrict__ Wq, const unsigned short* __restrict__ Wk,
    const unsigned short* __restrict__ Wv,
    const float* __restrict__ bq, const float* __restrict__ bk, const float* __restrict__ bv,
    unsigned short* __restrict__ Qo, unsigned short* __restrict__ Ko,
    unsigned short* __restrict__ Vt)
{
    __shared__ unsigned short sA[128 * 64];
    __shared__ unsigned short sB[128 * 64];
    const int z = blockIdx.z;
    const unsigned short* A = (z == 0) ? Xq : ((z == 1) ? Xk : Xv);
    const unsigned short* W = (z == 0) ? Wq : ((z == 1) ? Wk : Wv);
    const float* bias = (z == 0) ? bq : ((z == 1) ? bk : bv);
    const int m0 = blockIdx.y * 128, n0 = blockIdx.x * 128;

    f32x4 acc[4][4] = {};
    gemm_core_128(A, W, sA, sB, DM, m0, n0, acc);

    const int tid = threadIdx.x, wid = tid >> 6, lane = tid & 63;
    const int wr = wid >> 1, wc = wid & 1, fr = lane & 15, fg = lane >> 4;
    unsigned short* Oh = (z == 0) ? Qo : Ko;
    #pragma unroll
    for (int nf = 0; nf < 4; ++nf) {
        const int col = n0 + wc * 64 + nf * 16 + fr;
        const float bb = bias[col];
        const int h = col >> 6, dd = col & (DK - 1);
        #pragma unroll
        for (int mf = 0; mf < 4; ++mf) {
            #pragma unroll
            for (int r = 0; r < 4; ++r) {
                const int row = m0 + wr * 64 + mf * 16 + fg * 4 + r;
                const int b = row >> 11, s = row & (S_LEN - 1);
                const float val = acc[mf][nf][r] + bb;
                if (z < 2)
                    Oh[(((size_t)b * NH + h) * S_LEN + s) * DK + dd] = f2bf(val);
                else
                    Vt[(((size_t)b * NH + h) * DK + dd) * S_LEN + s] = f2bf(val);
            }
        }
    }
}

// ---------------- final output projection: BM=64 tile, fp32 out + bias -----
// Grid 8x64 = 512 blocks at 2/CU: restores cross-block overlap (the 256-block
// 128^2 version was exactly 1/CU -> fully exposed barrier drains).
// 4 waves, each a 32x64 quadrant: acc[2][4].
__global__ __launch_bounds__(256, 2) void gemm_out(
    const unsigned short* __restrict__ A, const unsigned short* __restrict__ W,
    const float* __restrict__ bias, float* __restrict__ out)
{
    __shared__ unsigned short sA[64 * 64];
    __shared__ unsigned short sB[128 * 64];

    const int tid = threadIdx.x;
    const int wid = tid >> 6, lane = tid & 63;
    const int wr = wid >> 1, wc = wid & 1;
    const int fr = lane & 15, fg = lane >> 4;
    const int ldr = lane >> 3, ldc = (lane & 7) * 8;
    const int m0 = blockIdx.y * 64, n0 = blockIdx.x * 128;

    const unsigned short* pA = A + (size_t)(m0 + ldr) * DM + ldc;
    const unsigned short* pW = W + (size_t)(n0 + ldr) * DM + ldc;

    f32x4 acc[2][4] = {};

    for (int k0 = 0; k0 < DM; k0 += 64) {
        __syncthreads();
        #pragma unroll
        for (int it = 0; it < 2; ++it) {       // A: 64 rows total
            const int rb = wid * 16 + it * 8;
            gload_lds16(pA + (size_t)rb * DM + k0, sA + rb * 64);
        }
        #pragma unroll
        for (int it = 0; it < 4; ++it) {       // B: 128 rows total
            const int rb = wid * 32 + it * 8;
            gload_lds16(pW + (size_t)rb * DM + k0, sB + rb * 64);
        }
        __syncthreads();
        #pragma unroll
        for (int kf = 0; kf < 2; ++kf) {
            bf16x8 af[2], bfr[4];
            #pragma unroll
            for (int mf = 0; mf < 2; ++mf)
                af[mf] = *(const bf16x8*)(sA + (wr * 32 + mf * 16 + fr) * 64 + kf * 32 + fg * 8);
            #pragma unroll
            for (int nf = 0; nf < 4; ++nf)
                bfr[nf] = *(const bf16x8*)(sB + (wc * 64 + nf * 16 + fr) * 64 + kf * 32 + fg * 8);
            #pragma unroll
            for (int mf = 0; mf < 2; ++mf)
                #pragma unroll
                for (int nf = 0; nf < 4; ++nf)
                    acc[mf][nf] = mfma16(af[mf], bfr[nf], acc[mf][nf]);
        }
    }

    #pragma unroll
    for (int nf = 0; nf < 4; ++nf) {
        const int col = n0 + wc * 64 + nf * 16 + fr;
        const float bb = bias[col];
        #pragma unroll
        for (int mf = 0; mf < 2; ++mf) {
            #pragma unroll
            for (int r = 0; r < 4; ++r) {
                const int row = m0 + wr * 32 + mf * 16 + fg * 4 + r;
                out[(size_t)row * DM + col] = acc[mf][nf][r] + bb;
            }
        }
    }
}

// ---------------- banded flash attention ----------------------------------
// Block = (b,h,q-tile of 128). 4 waves x 32 q-rows. Key tiles t in {0,1,2}
// at kt0 = q0 + (t-1)*128 (edge tiles skipped); mask: -128 <= j - i < 128.
__global__ __launch_bounds__(256, 2) void attn_kernel(
    const unsigned short* __restrict__ Qb,   // [B,H,S,64]
    const unsigned short* __restrict__ Kb,   // [B,H,S,64]
    const unsigned short* __restrict__ Vt,   // [B,H,64,S]
    unsigned short* __restrict__ Oout)       // [B*S, 1024] token-major
{
    __shared__ unsigned short sK[128 * 64];
    __shared__ unsigned short sV[64 * 128];
    __shared__ unsigned short sP[4][32 * 128];

    const int tid = threadIdx.x, wid = tid >> 6, lane = tid & 63;
    const int fr = lane & 15, fg = lane >> 4;
    const int qt = blockIdx.x, bh = blockIdx.y;
    const int q0 = qt * 128;
    const size_t base = (size_t)bh * (S_LEN * DK);

    bf16x8 qf[2][2];
    #pragma unroll
    for (int mf = 0; mf < 2; ++mf)
        #pragma unroll
        for (int kf = 0; kf < 2; ++kf)
            qf[mf][kf] = *(const bf16x8*)(Qb + base +
                (size_t)(q0 + wid * 32 + mf * 16 + fr) * DK + kf * 32 + fg * 8);

    f32x4 oacc[2][4] = {};
    float m_run[2][4], l_run[2][4];
    #pragma unroll
    for (int mf = 0; mf < 2; ++mf)
        #pragma unroll
        for (int r = 0; r < 4; ++r) { m_run[mf][r] = NEG_BIG; l_run[mf][r] = 0.f; }

    const int t_lo = (qt == 0) ? 1 : 0;
    const int t_hi = (qt == (S_LEN / 128 - 1)) ? 1 : 2;

    for (int t = t_lo; t <= t_hi; ++t) {
        const int kt0 = q0 + (t - 1) * 128;
        __syncthreads();
        {
            const unsigned short* gK = Kb + base + (size_t)kt0 * DK;
            #pragma unroll
            for (int it = 0; it < 4; ++it) {
                const int chunk = wid * 4 + it;
                gload_lds16(gK + chunk * 512 + lane * 8, sK + chunk * 512);
            }
            const unsigned short* gV = Vt + base + kt0;
            #pragma unroll
            for (int it = 0; it < 4; ++it) {
                const int chunk = wid * 4 + it;
                gload_lds16(gV + (size_t)(chunk * 4 + fg) * S_LEN + fr * 8, sV + chunk * 512);
            }
        }
        __syncthreads();

        f32x4 sacc[2][8] = {};
        #pragma unroll
        for (int kf = 0; kf < 2; ++kf) {
            bf16x8 kfr[8];
            #pragma unroll
            for (int nf = 0; nf < 8; ++nf)
                kfr[nf] = *(const bf16x8*)(sK + (nf * 16 + fr) * 64 + kf * 32 + fg * 8);
            #pragma unroll
            for (int mf = 0; mf < 2; ++mf)
                #pragma unroll
                for (int nf = 0; nf < 8; ++nf)
                    sacc[mf][nf] = mfma16(qf[mf][kf], kfr[nf], sacc[mf][nf]);
        }

        const int dt = (t - 1) * 128;
        #pragma unroll
        for (int mf = 0; mf < 2; ++mf) {
            #pragma unroll
            for (int r = 0; r < 4; ++r) {
                const int row = wid * 32 + mf * 16 + fg * 4 + r;
                float mm = NEG_BIG;
                #pragma unroll
                for (int nf = 0; nf < 8; ++nf) {
                    const int col = nf * 16 + fr;
                    const int diff = dt + col - row;
                    float s = sacc[mf][nf][r] * QK_SCALE;
                    s = (diff >= -128 && diff < 128) ? s : NEG_BIG;
                    sacc[mf][nf][r] = s;
                    mm = fmaxf(mm, s);
                }
                #pragma unroll
                for (int d = 1; d < 16; d <<= 1) mm = fmaxf(mm, __shfl_xor(mm, d));
                const float mold = m_run[mf][r];
                const float mn = fmaxf(mold, mm);
                m_run[mf][r] = mn;
                const float alpha = __expf(mold - mn);
                float ps = 0.f;
                #pragma unroll
                for (int nf = 0; nf < 8; ++nf) {
                    const float p = __expf(sacc[mf][nf][r] - mn);
                    ps += p;
                    sP[wid][(mf * 16 + fg * 4 + r) * 128 + nf * 16 + fr] = f2bf(p);
                }
                #pragma unroll
                for (int d = 1; d < 16; d <<= 1) ps += __shfl_xor(ps, d);
                l_run[mf][r] = l_run[mf][r] * alpha + ps;
                #pragma unroll
                for (int nf = 0; nf < 4; ++nf)
                    oacc[mf][nf][r] = oacc[mf][nf][r] * alpha;
            }
        }

        #pragma unroll
        for (int kf = 0; kf < 4; ++kf) {
            bf16x8 pa[2], vb[4];
            #pragma unroll
            for (int mf = 0; mf < 2; ++mf)
                pa[mf] = *(const bf16x8*)(&sP[wid][(mf * 16 + fr) * 128 + kf * 32 + fg * 8]);
            #pragma unroll
            for (int nf = 0; nf < 4; ++nf)
                vb[nf] = *(const bf16x8*)(sV + (nf * 16 + fr) * 128 + kf * 32 + fg * 8);
            #pragma unroll
            for (int mf = 0; mf < 2; ++mf)
                #pragma unroll
                for (int nf = 0; nf < 4; ++nf)
                    oacc[mf][nf] = mfma16(pa[mf], vb[nf], oacc[mf][nf]);
        }
    }

    const int b = bh >> 4, h = bh & 15;
    #pragma unroll
    for (int mf = 0; mf < 2; ++mf) {
        #pragma unroll
        for (int r = 0; r < 4; ++r) {
            const float inv = 1.0f / l_run[mf][r];
            const int token = b * S_LEN + q0 + wid * 32 + mf * 16 + fg * 4 + r;
            #pragma unroll
            for (int nf = 0; nf < 4; ++nf) {
                const int feat = h * 64 + nf * 16 + fr;
                Oout[(size_t)token * DM + feat] = f2bf(oacc[mf][nf][r] * inv);
            }
        }
    }
}

// ---------------------------------------------------------------------------
extern "C" void kernel_launch(void* const* d_in, const int* in_sizes, int n_in,
                              void* d_out, int out_size, void* d_ws, size_t ws_size,
                              hipStream_t stream)
{
    (void)in_sizes; (void)n_in; (void)out_size; (void)ws_size;
    const float* q  = (const float*)d_in[0];
    const float* k  = (const float*)d_in[1];
    const float* v  = (const float*)d_in[2];
    const float* Wq = (const float*)d_in[3];
    const float* bq = (const float*)d_in[4];
    const float* Wk = (const float*)d_in[5];
    const float* bk = (const float*)d_in[6];
    const float* Wv = (const float*)d_in[7];
    const float* bv = (const float*)d_in[8];
    const float* Wo = (const float*)d_in[9];
    const float* bo = (const float*)d_in[10];

    char* ws = (char*)d_ws;
    const size_t MB = 1024 * 1024;
    unsigned short* Xq  = (unsigned short*)(ws + 0 * MB);   // 8 MiB, later reused as attn-out
    unsigned short* Xk  = (unsigned short*)(ws + 8 * MB);   // 8 MiB
    unsigned short* Xv  = (unsigned short*)(ws + 16 * MB);  // 8 MiB
    unsigned short* Qb  = (unsigned short*)(ws + 24 * MB);  // 8 MiB
    unsigned short* Kb  = (unsigned short*)(ws + 32 * MB);  // 8 MiB
    unsigned short* Vt  = (unsigned short*)(ws + 40 * MB);  // 8 MiB
    unsigned short* Wqb = (unsigned short*)(ws + 48 * MB);  // 2 MiB
    unsigned short* Wkb = (unsigned short*)(ws + 50 * MB);  // 2 MiB
    unsigned short* Wvb = (unsigned short*)(ws + 52 * MB);  // 2 MiB
    unsigned short* Wob = (unsigned short*)(ws + 54 * MB);  // 2 MiB
    unsigned short* AO  = Xq;  // attn output aliases Xq (free after Q-projection)

    CvtArgs ca;
    ca.src[0] = q;  ca.dst[0] = Xq;  ca.n8[0] = (NB * S_LEN * DM) / 8;
    ca.src[1] = k;  ca.dst[1] = Xk;  ca.n8[1] = (NB * S_LEN * DM) / 8;
    ca.src[2] = v;  ca.dst[2] = Xv;  ca.n8[2] = (NB * S_LEN * DM) / 8;
    ca.src[3] = Wq; ca.dst[3] = Wqb; ca.n8[3] = (DM * DM) / 8;
    ca.src[4] = Wk; ca.dst[4] = Wkb; ca.n8[4] = (DM * DM) / 8;
    ca.src[5] = Wv; ca.dst[5] = Wvb; ca.n8[5] = (DM * DM) / 8;
    ca.src[6] = Wo; ca.dst[6] = Wob; ca.n8[6] = (DM * DM) / 8;
    cvt_f32_bf16<<<dim3(1024, 7), 256, 0, stream>>>(ca);

    gemm_qkv<<<dim3(DM / 128, (NB * S_LEN) / 128, 3), 256, 0, stream>>>(
        Xq, Xk, Xv, Wqb, Wkb, Wvb, bq, bk, bv, Qb, Kb, Vt);

    attn_kernel<<<dim3(S_LEN / 128, NB * NH), 256, 0, stream>>>(Qb, Kb, Vt, AO);

    gemm_out<<<dim3(DM / 128, (NB * S_LEN) / 64), 256, 0, stream>>>(
        AO, Wob, bo, (float*)d_out);
}

// Round 7
// 109.126 us; speedup vs baseline: 1.3229x; 1.0367x over previous
//
#include <hip/hip_runtime.h>
#include <stdint.h>

#define S_LEN 2048
#define NB 2
#define NH 16
#define DK 64
#define DM 1024
#define QK_SCALE 0.125f
#define NEG_BIG -1e30f

typedef __attribute__((ext_vector_type(8))) short bf16x8;
typedef __attribute__((ext_vector_type(4))) float f32x4;

static __device__ __forceinline__ f32x4 mfma16(bf16x8 a, bf16x8 b, f32x4 c) {
    return __builtin_amdgcn_mfma_f32_16x16x32_bf16(a, b, c, 0, 0, 0);
}

// async global->LDS, 16B per lane; dst is wave-uniform base, HW adds lane*16
static __device__ __forceinline__ void gload_lds16(const void* g, void* l) {
    __builtin_amdgcn_global_load_lds((const __attribute__((address_space(1))) void*)g,
                                     (__attribute__((address_space(3))) void*)l,
                                     16, 0, 0);
}

// fp32 -> bf16 bits, RNE (inputs always finite here)
static __device__ __forceinline__ unsigned short f2bf(float x) {
    unsigned int u = __float_as_uint(x);
    u += 0x7fffu + ((u >> 16) & 1u);
    return (unsigned short)(u >> 16);
}

// ---------------- conversion: fp32 -> bf16, 7 tensors in one launch -------
struct CvtArgs {
    const float* src[7];
    unsigned short* dst[7];
    int n8[7];
};

__global__ __launch_bounds__(256) void cvt_f32_bf16(CvtArgs a) {
    const int t = blockIdx.y;
    const float* __restrict__ src = a.src[t];
    unsigned short* __restrict__ dst = a.dst[t];
    const int n8 = a.n8[t];
    const int stride = gridDim.x * blockDim.x;
    for (int i = blockIdx.x * blockDim.x + threadIdx.x; i < n8; i += stride) {
        float4 v0 = ((const float4*)src)[(size_t)i * 2];
        float4 v1 = ((const float4*)src)[(size_t)i * 2 + 1];
        union { bf16x8 v; unsigned short h[8]; } u;
        u.h[0] = f2bf(v0.x); u.h[1] = f2bf(v0.y); u.h[2] = f2bf(v0.z); u.h[3] = f2bf(v0.w);
        u.h[4] = f2bf(v1.x); u.h[5] = f2bf(v1.y); u.h[6] = f2bf(v1.z); u.h[7] = f2bf(v1.w);
        ((bf16x8*)dst)[i] = u.v;
    }
}

// ---------------- GEMM core: C[128x128] = A[M,K] * W[N,K]^T ----------------
// m97-structure: 128^2 tile, BK=64, global_load_lds(16B), 2 barriers/K-step,
// PLUS the r3-verified T2 swizzle: LDS dest stays linear, GLOBAL source
// chunk pre-swizzled by ^(row&7); fragment ds_reads use chunk^(fr&7).
// PMC-verified conflict-free (round 3: 9.4M -> 0).
static __device__ __forceinline__ void gemm_core_128(
    const unsigned short* __restrict__ A,
    const unsigned short* __restrict__ W,
    unsigned short* sA, unsigned short* sB,
    int K, int m0, int n0, f32x4 acc[4][4])
{
    const int tid = threadIdx.x;
    const int wid = tid >> 6, lane = tid & 63;
    const int wr = wid >> 1, wc = wid & 1;
    const int fr = lane & 15, fg = lane >> 4;
    // staging: lane covers row (rb + lane>>3), LDS chunk lane&7; global source
    // chunk pre-swizzled so linear LDS holds the swizzled layout. rb%8==0 so
    // row&7 == lane>>3.
    const int ldr = lane >> 3;
    const int ldc = ((lane & 7) ^ (lane >> 3)) * 8;

    const unsigned short* pA = A + (size_t)(m0 + ldr) * K + ldc;
    const unsigned short* pW = W + (size_t)(n0 + ldr) * K + ldc;

    // fragment-read swizzled chunk offsets; frag row&7 == fr&7 for A and B
    const int cka0 = ((0 + fg) ^ (fr & 7)) * 8;   // kf=0: chunks 0..3
    const int cka1 = ((4 + fg) ^ (fr & 7)) * 8;   // kf=1: chunks 4..7

    for (int k0 = 0; k0 < K; k0 += 64) {
        __syncthreads();  // previous compute done reading LDS
        #pragma unroll
        for (int it = 0; it < 4; ++it) {
            const int rb = wid * 32 + it * 8;   // 8 rows per call (64 lanes * 16B)
            gload_lds16(pA + (size_t)(rb)*K + k0, sA + rb * 64);
            gload_lds16(pW + (size_t)(rb)*K + k0, sB + rb * 64);
        }
        __syncthreads();  // implies s_waitcnt vmcnt(0): staged data visible
        #pragma unroll
        for (int kf = 0; kf < 2; ++kf) {
            const int cka = kf ? cka1 : cka0;
            bf16x8 af[4], bfr[4];
            #pragma unroll
            for (int mf = 0; mf < 4; ++mf)
                af[mf] = *(const bf16x8*)(sA + (wr * 64 + mf * 16 + fr) * 64 + cka);
            #pragma unroll
            for (int nf = 0; nf < 4; ++nf)
                bfr[nf] = *(const bf16x8*)(sB + (wc * 64 + nf * 16 + fr) * 64 + cka);
            #pragma unroll
            for (int mf = 0; mf < 4; ++mf)
                #pragma unroll
                for (int nf = 0; nf < 4; ++nf)
                    acc[mf][nf] = mfma16(af[mf], bfr[nf], acc[mf][nf]);
        }
    }
}

// ---------------- merged QKV projection (grid.z selects Q/K/V) -------------
// z=0: Q -> [B,H,S,dk]; z=1: K -> [B,H,S,dk]; z=2: V -> [B,H,dk,S] (transposed)
__global__ __launch_bounds__(256, 3) void gemm_qkv(
    const unsigned short* __restrict__ Xq, const unsigned short* __restrict__ Xk,
    const unsigned short* __restrict__ Xv,
    const unsigned short* __restrict__ Wq, const unsigned short* __restrict__ Wk,
    const unsigned short* __restrict__ Wv,
    const float* __restrict__ bq, const float* __restrict__ bk, const float* __restrict__ bv,
    unsigned short* __restrict__ Qo, unsigned short* __restrict__ Ko,
    unsigned short* __restrict__ Vt)
{
    __shared__ unsigned short sA[128 * 64];
    __shared__ unsigned short sB[128 * 64];
    const int z = blockIdx.z;
    const unsigned short* A = (z == 0) ? Xq : ((z == 1) ? Xk : Xv);
    const unsigned short* W = (z == 0) ? Wq : ((z == 1) ? Wk : Wv);
    const float* bias = (z == 0) ? bq : ((z == 1) ? bk : bv);
    const int m0 = blockIdx.y * 128, n0 = blockIdx.x * 128;

    f32x4 acc[4][4] = {};
    gemm_core_128(A, W, sA, sB, DM, m0, n0, acc);

    const int tid = threadIdx.x, wid = tid >> 6, lane = tid & 63;
    const int wr = wid >> 1, wc = wid & 1, fr = lane & 15, fg = lane >> 4;
    unsigned short* Oh = (z == 0) ? Qo : Ko;
    #pragma unroll
    for (int nf = 0; nf < 4; ++nf) {
        const int col = n0 + wc * 64 + nf * 16 + fr;
        const float bb = bias[col];
        const int h = col >> 6, dd = col & (DK - 1);
        #pragma unroll
        for (int mf = 0; mf < 4; ++mf) {
            #pragma unroll
            for (int r = 0; r < 4; ++r) {
                const int row = m0 + wr * 64 + mf * 16 + fg * 4 + r;
                const int b = row >> 11, s = row & (S_LEN - 1);
                const float val = acc[mf][nf][r] + bb;
                if (z < 2)
                    Oh[(((size_t)b * NH + h) * S_LEN + s) * DK + dd] = f2bf(val);
                else
                    Vt[(((size_t)b * NH + h) * DK + dd) * S_LEN + s] = f2bf(val);
            }
        }
    }
}

// ---------------- final output projection: BM=64 tile, fp32 out + bias -----
// 512 blocks at 2/CU; same T2 swizzle as gemm_core_128.
__global__ __launch_bounds__(256, 2) void gemm_out(
    const unsigned short* __restrict__ A, const unsigned short* __restrict__ W,
    const float* __restrict__ bias, float* __restrict__ out)
{
    __shared__ unsigned short sA[64 * 64];
    __shared__ unsigned short sB[128 * 64];

    const int tid = threadIdx.x;
    const int wid = tid >> 6, lane = tid & 63;
    const int wr = wid >> 1, wc = wid & 1;
    const int fr = lane & 15, fg = lane >> 4;
    const int ldr = lane >> 3;
    const int ldc = ((lane & 7) ^ (lane >> 3)) * 8;
    const int m0 = blockIdx.y * 64, n0 = blockIdx.x * 128;

    const unsigned short* pA = A + (size_t)(m0 + ldr) * DM + ldc;
    const unsigned short* pW = W + (size_t)(n0 + ldr) * DM + ldc;

    const int cka0 = ((0 + fg) ^ (fr & 7)) * 8;
    const int cka1 = ((4 + fg) ^ (fr & 7)) * 8;

    f32x4 acc[2][4] = {};

    for (int k0 = 0; k0 < DM; k0 += 64) {
        __syncthreads();
        #pragma unroll
        for (int it = 0; it < 2; ++it) {       // A: 64 rows total
            const int rb = wid * 16 + it * 8;
            gload_lds16(pA + (size_t)rb * DM + k0, sA + rb * 64);
        }
        #pragma unroll
        for (int it = 0; it < 4; ++it) {       // B: 128 rows total
            const int rb = wid * 32 + it * 8;
            gload_lds16(pW + (size_t)rb * DM + k0, sB + rb * 64);
        }
        __syncthreads();
        #pragma unroll
        for (int kf = 0; kf < 2; ++kf) {
            const int cka = kf ? cka1 : cka0;
            bf16x8 af[2], bfr[4];
            #pragma unroll
            for (int mf = 0; mf < 2; ++mf)
                af[mf] = *(const bf16x8*)(sA + (wr * 32 + mf * 16 + fr) * 64 + cka);
            #pragma unroll
            for (int nf = 0; nf < 4; ++nf)
                bfr[nf] = *(const bf16x8*)(sB + (wc * 64 + nf * 16 + fr) * 64 + cka);
            #pragma unroll
            for (int mf = 0; mf < 2; ++mf)
                #pragma unroll
                for (int nf = 0; nf < 4; ++nf)
                    acc[mf][nf] = mfma16(af[mf], bfr[nf], acc[mf][nf]);
        }
    }

    #pragma unroll
    for (int nf = 0; nf < 4; ++nf) {
        const int col = n0 + wc * 64 + nf * 16 + fr;
        const float bb = bias[col];
        #pragma unroll
        for (int mf = 0; mf < 2; ++mf) {
            #pragma unroll
            for (int r = 0; r < 4; ++r) {
                const int row = m0 + wr * 32 + mf * 16 + fg * 4 + r;
                out[(size_t)row * DM + col] = acc[mf][nf][r] + bb;
            }
        }
    }
}

// ---------------- banded flash attention ----------------------------------
// Block = (b,h,q-tile of 128). 4 waves x 32 q-rows. Key tiles t in {0,1,2}
// at kt0 = q0 + (t-1)*128 (edge tiles skipped); mask: -128 <= j - i < 128.
__global__ __launch_bounds__(256, 2) void attn_kernel(
    const unsigned short* __restrict__ Qb,   // [B,H,S,64]
    const unsigned short* __restrict__ Kb,   // [B,H,S,64]
    const unsigned short* __restrict__ Vt,   // [B,H,64,S]
    unsigned short* __restrict__ Oout)       // [B*S, 1024] token-major
{
    __shared__ unsigned short sK[128 * 64];
    __shared__ unsigned short sV[64 * 128];
    __shared__ unsigned short sP[4][32 * 128];

    const int tid = threadIdx.x, wid = tid >> 6, lane = tid & 63;
    const int fr = lane & 15, fg = lane >> 4;
    const int qt = blockIdx.x, bh = blockIdx.y;
    const int q0 = qt * 128;
    const size_t base = (size_t)bh * (S_LEN * DK);

    bf16x8 qf[2][2];
    #pragma unroll
    for (int mf = 0; mf < 2; ++mf)
        #pragma unroll
        for (int kf = 0; kf < 2; ++kf)
            qf[mf][kf] = *(const bf16x8*)(Qb + base +
                (size_t)(q0 + wid * 32 + mf * 16 + fr) * DK + kf * 32 + fg * 8);

    f32x4 oacc[2][4] = {};
    float m_run[2][4], l_run[2][4];
    #pragma unroll
    for (int mf = 0; mf < 2; ++mf)
        #pragma unroll
        for (int r = 0; r < 4; ++r) { m_run[mf][r] = NEG_BIG; l_run[mf][r] = 0.f; }

    const int t_lo = (qt == 0) ? 1 : 0;
    const int t_hi = (qt == (S_LEN / 128 - 1)) ? 1 : 2;

    for (int t = t_lo; t <= t_hi; ++t) {
        const int kt0 = q0 + (t - 1) * 128;
        __syncthreads();
        {
            const unsigned short* gK = Kb + base + (size_t)kt0 * DK;
            #pragma unroll
            for (int it = 0; it < 4; ++it) {
                const int chunk = wid * 4 + it;
                gload_lds16(gK + chunk * 512 + lane * 8, sK + chunk * 512);
            }
            const unsigned short* gV = Vt + base + kt0;
            #pragma unroll
            for (int it = 0; it < 4; ++it) {
                const int chunk = wid * 4 + it;
                gload_lds16(gV + (size_t)(chunk * 4 + fg) * S_LEN + fr * 8, sV + chunk * 512);
            }
        }
        __syncthreads();

        f32x4 sacc[2][8] = {};
        #pragma unroll
        for (int kf = 0; kf < 2; ++kf) {
            bf16x8 kfr[8];
            #pragma unroll
            for (int nf = 0; nf < 8; ++nf)
                kfr[nf] = *(const bf16x8*)(sK + (nf * 16 + fr) * 64 + kf * 32 + fg * 8);
            #pragma unroll
            for (int mf = 0; mf < 2; ++mf)
                #pragma unroll
                for (int nf = 0; nf < 8; ++nf)
                    sacc[mf][nf] = mfma16(qf[mf][kf], kfr[nf], sacc[mf][nf]);
        }

        const int dt = (t - 1) * 128;
        #pragma unroll
        for (int mf = 0; mf < 2; ++mf) {
            #pragma unroll
            for (int r = 0; r < 4; ++r) {
                const int row = wid * 32 + mf * 16 + fg * 4 + r;
                float mm = NEG_BIG;
                #pragma unroll
                for (int nf = 0; nf < 8; ++nf) {
                    const int col = nf * 16 + fr;
                    const int diff = dt + col - row;
                    float s = sacc[mf][nf][r] * QK_SCALE;
                    s = (diff >= -128 && diff < 128) ? s : NEG_BIG;
                    sacc[mf][nf][r] = s;
                    mm = fmaxf(mm, s);
                }
                #pragma unroll
                for (int d = 1; d < 16; d <<= 1) mm = fmaxf(mm, __shfl_xor(mm, d));
                const float mold = m_run[mf][r];
                const float mn = fmaxf(mold, mm);
                m_run[mf][r] = mn;
                const float alpha = __expf(mold - mn);
                float ps = 0.f;
                #pragma unroll
                for (int nf = 0; nf < 8; ++nf) {
                    const float p = __expf(sacc[mf][nf][r] - mn);
                    ps += p;
                    sP[wid][(mf * 16 + fg * 4 + r) * 128 + nf * 16 + fr] = f2bf(p);
                }
                #pragma unroll
                for (int d = 1; d < 16; d <<= 1) ps += __shfl_xor(ps, d);
                l_run[mf][r] = l_run[mf][r] * alpha + ps;
                #pragma unroll
                for (int nf = 0; nf < 4; ++nf)
                    oacc[mf][nf][r] = oacc[mf][nf][r] * alpha;
            }
        }

        #pragma unroll
        for (int kf = 0; kf < 4; ++kf) {
            bf16x8 pa[2], vb[4];
            #pragma unroll
            for (int mf = 0; mf < 2; ++mf)
                pa[mf] = *(const bf16x8*)(&sP[wid][(mf * 16 + fr) * 128 + kf * 32 + fg * 8]);
            #pragma unroll
            for (int nf = 0; nf < 4; ++nf)
                vb[nf] = *(const bf16x8*)(sV + (nf * 16 + fr) * 128 + kf * 32 + fg * 8);
            #pragma unroll
            for (int mf = 0; mf < 2; ++mf)
                #pragma unroll
                for (int nf = 0; nf < 4; ++nf)
                    oacc[mf][nf] = mfma16(pa[mf], vb[nf], oacc[mf][nf]);
        }
    }

    const int b = bh >> 4, h = bh & 15;
    #pragma unroll
    for (int mf = 0; mf < 2; ++mf) {
        #pragma unroll
        for (int r = 0; r < 4; ++r) {
            const float inv = 1.0f / l_run[mf][r];
            const int token = b * S_LEN + q0 + wid * 32 + mf * 16 + fg * 4 + r;
            #pragma unroll
            for (int nf = 0; nf < 4; ++nf) {
                const int feat = h * 64 + nf * 16 + fr;
                Oout[(size_t)token * DM + feat] = f2bf(oacc[mf][nf][r] * inv);
            }
        }
    }
}

// ---------------------------------------------------------------------------
extern "C" void kernel_launch(void* const* d_in, const int* in_sizes, int n_in,
                              void* d_out, int out_size, void* d_ws, size_t ws_size,
                              hipStream_t stream)
{
    (void)in_sizes; (void)n_in; (void)out_size; (void)ws_size;
    const float* q  = (const float*)d_in[0];
    const float* k  = (const float*)d_in[1];
    const float* v  = (const float*)d_in[2];
    const float* Wq = (const float*)d_in[3];
    const float* bq = (const float*)d_in[4];
    const float* Wk = (const float*)d_in[5];
    const float* bk = (const float*)d_in[6];
    const float* Wv = (const float*)d_in[7];
    const float* bv = (const float*)d_in[8];
    const float* Wo = (const float*)d_in[9];
    const float* bo = (const float*)d_in[10];

    char* ws = (char*)d_ws;
    const size_t MB = 1024 * 1024;
    unsigned short* Xq  = (unsigned short*)(ws + 0 * MB);   // 8 MiB, later reused as attn-out
    unsigned short* Xk  = (unsigned short*)(ws + 8 * MB);   // 8 MiB
    unsigned short* Xv  = (unsigned short*)(ws + 16 * MB);  // 8 MiB
    unsigned short* Qb  = (unsigned short*)(ws + 24 * MB);  // 8 MiB
    unsigned short* Kb  = (unsigned short*)(ws + 32 * MB);  // 8 MiB
    unsigned short* Vt  = (unsigned short*)(ws + 40 * MB);  // 8 MiB
    unsigned short* Wqb = (unsigned short*)(ws + 48 * MB);  // 2 MiB
    unsigned short* Wkb = (unsigned short*)(ws + 50 * MB);  // 2 MiB
    unsigned short* Wvb = (unsigned short*)(ws + 52 * MB);  // 2 MiB
    unsigned short* Wob = (unsigned short*)(ws + 54 * MB);  // 2 MiB
    unsigned short* AO  = Xq;  // attn output aliases Xq (free after Q-projection)

    CvtArgs ca;
    ca.src[0] = q;  ca.dst[0] = Xq;  ca.n8[0] = (NB * S_LEN * DM) / 8;
    ca.src[1] = k;  ca.dst[1] = Xk;  ca.n8[1] = (NB * S_LEN * DM) / 8;
    ca.src[2] = v;  ca.dst[2] = Xv;  ca.n8[2] = (NB * S_LEN * DM) / 8;
    ca.src[3] = Wq; ca.dst[3] = Wqb; ca.n8[3] = (DM * DM) / 8;
    ca.src[4] = Wk; ca.dst[4] = Wkb; ca.n8[4] = (DM * DM) / 8;
    ca.src[5] = Wv; ca.dst[5] = Wvb; ca.n8[5] = (DM * DM) / 8;
    ca.src[6] = Wo; ca.dst[6] = Wob; ca.n8[6] = (DM * DM) / 8;
    cvt_f32_bf16<<<dim3(1024, 7), 256, 0, stream>>>(ca);

    gemm_qkv<<<dim3(DM / 128, (NB * S_LEN) / 128, 3), 256, 0, stream>>>(
        Xq, Xk, Xv, Wqb, Wkb, Wvb, bq, bk, bv, Qb, Kb, Vt);

    attn_kernel<<<dim3(S_LEN / 128, NB * NH), 256, 0, stream>>>(Qb, Kb, Vt, AO);

    gemm_out<<<dim3(DM / 128, (NB * S_LEN) / 64), 256, 0, stream>>>(
        AO, Wob, bo, (float*)d_out);
}

// Round 8
// 108.374 us; speedup vs baseline: 1.3321x; 1.0069x over previous
//
#include <hip/hip_runtime.h>
#include <stdint.h>

#define S_LEN 2048
#define NB 2
#define NH 16
#define DK 64
#define DM 1024
#define QK_SCALE 0.125f
#define NEG_BIG -1e30f

typedef __attribute__((ext_vector_type(8))) short bf16x8;
typedef __attribute__((ext_vector_type(4))) float f32x4;

static __device__ __forceinline__ f32x4 mfma16(bf16x8 a, bf16x8 b, f32x4 c) {
    return __builtin_amdgcn_mfma_f32_16x16x32_bf16(a, b, c, 0, 0, 0);
}

// async global->LDS, 16B per lane; dst is wave-uniform base, HW adds lane*16
static __device__ __forceinline__ void gload_lds16(const void* g, void* l) {
    __builtin_amdgcn_global_load_lds((const __attribute__((address_space(1))) void*)g,
                                     (__attribute__((address_space(3))) void*)l,
                                     16, 0, 0);
}

// fp32 -> bf16 bits, RNE (inputs always finite here)
static __device__ __forceinline__ unsigned short f2bf(float x) {
    unsigned int u = __float_as_uint(x);
    u += 0x7fffu + ((u >> 16) & 1u);
    return (unsigned short)(u >> 16);
}

// ---------------- conversion: fp32 -> bf16, 7 tensors in one launch -------
struct CvtArgs {
    const float* src[7];
    unsigned short* dst[7];
    int n8[7];
};

__global__ __launch_bounds__(256) void cvt_f32_bf16(CvtArgs a) {
    const int t = blockIdx.y;
    const float* __restrict__ src = a.src[t];
    unsigned short* __restrict__ dst = a.dst[t];
    const int n8 = a.n8[t];
    const int stride = gridDim.x * blockDim.x;
    for (int i = blockIdx.x * blockDim.x + threadIdx.x; i < n8; i += stride) {
        float4 v0 = ((const float4*)src)[(size_t)i * 2];
        float4 v1 = ((const float4*)src)[(size_t)i * 2 + 1];
        union { bf16x8 v; unsigned short h[8]; } u;
        u.h[0] = f2bf(v0.x); u.h[1] = f2bf(v0.y); u.h[2] = f2bf(v0.z); u.h[3] = f2bf(v0.w);
        u.h[4] = f2bf(v1.x); u.h[5] = f2bf(v1.y); u.h[6] = f2bf(v1.z); u.h[7] = f2bf(v1.w);
        ((bf16x8*)dst)[i] = u.v;
    }
}

// ---------------- merged QKV projection (grid.z selects Q/K/V) -------------
// 128^2 tile, BK=64, 4 waves, T2 swizzle (r7, PMC conflict-free) PLUS
// double-buffered LDS (2x32KB) with counted vmcnt (T3-minimum, T4):
//   STAGE(0)->buf0
//   for t: { t<15 ? [STAGE(t+1)->buf^1 ; vmcnt(8)] : vmcnt(0) }
//          s_barrier ; ds_read(buf)+MFMA ; s_barrier
// Loads for t+1 fly across the full compute of t -> per-step drain hidden.
// Barriers are asm with "memory" clobber so ds_reads can't hoist above sync.
// z=0: Q -> [B,H,S,dk]; z=1: K -> [B,H,S,dk]; z=2: V -> [B,H,dk,S].
__global__ __launch_bounds__(256, 2) void gemm_qkv(
    const unsigned short* __restrict__ Xq, const unsigned short* __restrict__ Xk,
    const unsigned short* __restrict__ Xv,
    const unsigned short* __restrict__ Wq, const unsigned short* __restrict__ Wk,
    const unsigned short* __restrict__ Wv,
    const float* __restrict__ bq, const float* __restrict__ bk, const float* __restrict__ bv,
    unsigned short* __restrict__ Qo, unsigned short* __restrict__ Ko,
    unsigned short* __restrict__ Vt)
{
    __shared__ unsigned short lds[32768];   // 64 KiB: [buf][A 8192][B 8192]

    const int tid = threadIdx.x;
    const int wid = tid >> 6, lane = tid & 63;
    const int wr = wid >> 1, wc = wid & 1;
    const int fr = lane & 15, fg = lane >> 4;
    const int z = blockIdx.z;
    const int m0 = blockIdx.y * 128, n0 = blockIdx.x * 128;

    const unsigned short* A = (z == 0) ? Xq : ((z == 1) ? Xk : Xv);
    const unsigned short* W = (z == 0) ? Wq : ((z == 1) ? Wk : Wv);
    const float* bias = (z == 0) ? bq : ((z == 1) ? bk : bv);

    // staging addressing with pre-swizzled global source (r7, verified)
    const int ldr = lane >> 3;
    const int ldc = ((lane & 7) ^ (lane >> 3)) * 8;
    const unsigned short* pA = A + (size_t)(m0 + ldr) * DM + ldc;
    const unsigned short* pW = W + (size_t)(n0 + ldr) * DM + ldc;

    // fragment-read swizzled chunk offsets (frag row&7 == fr&7)
    const int cka0 = ((0 + fg) ^ (fr & 7)) * 8;
    const int cka1 = ((4 + fg) ^ (fr & 7)) * 8;

    f32x4 acc[4][4] = {};

    // STAGE(t -> buffer b): 8 gload_lds per wave
    #define STAGE_QKV(T, B)                                                     \
        do {                                                                    \
            const int _k0 = (T) * 64;                                           \
            unsigned short* _dA = lds + (B) * 16384;                            \
            unsigned short* _dB = lds + (B) * 16384 + 8192;                     \
            _Pragma("unroll")                                                   \
            for (int _it = 0; _it < 4; ++_it) {                                 \
                const int _rb = wid * 32 + _it * 8;                             \
                gload_lds16(pA + (size_t)_rb * DM + _k0, _dA + _rb * 64);       \
                gload_lds16(pW + (size_t)_rb * DM + _k0, _dB + _rb * 64);       \
            }                                                                   \
        } while (0)

    STAGE_QKV(0, 0);

    for (int t = 0; t < 16; ++t) {
        const int b = t & 1;
        if (t < 15) {
            STAGE_QKV(t + 1, b ^ 1);
            asm volatile("s_waitcnt vmcnt(8)" ::: "memory");  // stage(t) landed
        } else {
            asm volatile("s_waitcnt vmcnt(0)" ::: "memory");
        }
        asm volatile("s_barrier" ::: "memory");  // publish buf b across waves

        const unsigned short* sA = lds + b * 16384;
        const unsigned short* sB = sA + 8192;
        #pragma unroll
        for (int kf = 0; kf < 2; ++kf) {
            const int cka = kf ? cka1 : cka0;
            bf16x8 af[4], bfr[4];
            #pragma unroll
            for (int mf = 0; mf < 4; ++mf)
                af[mf] = *(const bf16x8*)(sA + (wr * 64 + mf * 16 + fr) * 64 + cka);
            #pragma unroll
            for (int nf = 0; nf < 4; ++nf)
                bfr[nf] = *(const bf16x8*)(sB + (wc * 64 + nf * 16 + fr) * 64 + cka);
            #pragma unroll
            for (int mf = 0; mf < 4; ++mf)
                #pragma unroll
                for (int nf = 0; nf < 4; ++nf)
                    acc[mf][nf] = mfma16(af[mf], bfr[nf], acc[mf][nf]);
        }
        // reads of buf b retired (lgkm waits precede the MFMAs above);
        // barrier so next iter may overwrite buf b^... (stage t+2 -> buf b)
        asm volatile("s_barrier" ::: "memory");
    }
    #undef STAGE_QKV

    // epilogue (identical to r7)
    unsigned short* Oh = (z == 0) ? Qo : Ko;
    #pragma unroll
    for (int nf = 0; nf < 4; ++nf) {
        const int col = n0 + wc * 64 + nf * 16 + fr;
        const float bb = bias[col];
        const int h = col >> 6, dd = col & (DK - 1);
        #pragma unroll
        for (int mf = 0; mf < 4; ++mf) {
            #pragma unroll
            for (int r = 0; r < 4; ++r) {
                const int row = m0 + wr * 64 + mf * 16 + fg * 4 + r;
                const int bb_ = row >> 11, s = row & (S_LEN - 1);
                const float val = acc[mf][nf][r] + bb;
                if (z < 2)
                    Oh[(((size_t)bb_ * NH + h) * S_LEN + s) * DK + dd] = f2bf(val);
                else
                    Vt[(((size_t)bb_ * NH + h) * DK + dd) * S_LEN + s] = f2bf(val);
            }
        }
    }
}

// ---------------- final output projection: BM=64 tile, fp32 out + bias -----
// (unchanged from r7: 512 blocks at 2/CU, T2 swizzle, 2-barrier loop)
__global__ __launch_bounds__(256, 2) void gemm_out(
    const unsigned short* __restrict__ A, const unsigned short* __restrict__ W,
    const float* __restrict__ bias, float* __restrict__ out)
{
    __shared__ unsigned short sA[64 * 64];
    __shared__ unsigned short sB[128 * 64];

    const int tid = threadIdx.x;
    const int wid = tid >> 6, lane = tid & 63;
    const int wr = wid >> 1, wc = wid & 1;
    const int fr = lane & 15, fg = lane >> 4;
    const int ldr = lane >> 3;
    const int ldc = ((lane & 7) ^ (lane >> 3)) * 8;
    const int m0 = blockIdx.y * 64, n0 = blockIdx.x * 128;

    const unsigned short* pA = A + (size_t)(m0 + ldr) * DM + ldc;
    const unsigned short* pW = W + (size_t)(n0 + ldr) * DM + ldc;

    const int cka0 = ((0 + fg) ^ (fr & 7)) * 8;
    const int cka1 = ((4 + fg) ^ (fr & 7)) * 8;

    f32x4 acc[2][4] = {};

    for (int k0 = 0; k0 < DM; k0 += 64) {
        __syncthreads();
        #pragma unroll
        for (int it = 0; it < 2; ++it) {       // A: 64 rows total
            const int rb = wid * 16 + it * 8;
            gload_lds16(pA + (size_t)rb * DM + k0, sA + rb * 64);
        }
        #pragma unroll
        for (int it = 0; it < 4; ++it) {       // B: 128 rows total
            const int rb = wid * 32 + it * 8;
            gload_lds16(pW + (size_t)rb * DM + k0, sB + rb * 64);
        }
        __syncthreads();
        #pragma unroll
        for (int kf = 0; kf < 2; ++kf) {
            const int cka = kf ? cka1 : cka0;
            bf16x8 af[2], bfr[4];
            #pragma unroll
            for (int mf = 0; mf < 2; ++mf)
                af[mf] = *(const bf16x8*)(sA + (wr * 32 + mf * 16 + fr) * 64 + cka);
            #pragma unroll
            for (int nf = 0; nf < 4; ++nf)
                bfr[nf] = *(const bf16x8*)(sB + (wc * 64 + nf * 16 + fr) * 64 + cka);
            #pragma unroll
            for (int mf = 0; mf < 2; ++mf)
                #pragma unroll
                for (int nf = 0; nf < 4; ++nf)
                    acc[mf][nf] = mfma16(af[mf], bfr[nf], acc[mf][nf]);
        }
    }

    #pragma unroll
    for (int nf = 0; nf < 4; ++nf) {
        const int col = n0 + wc * 64 + nf * 16 + fr;
        const float bb = bias[col];
        #pragma unroll
        for (int mf = 0; mf < 2; ++mf) {
            #pragma unroll
            for (int r = 0; r < 4; ++r) {
                const int row = m0 + wr * 32 + mf * 16 + fg * 4 + r;
                out[(size_t)row * DM + col] = acc[mf][nf][r] + bb;
            }
        }
    }
}

// ---------------- banded flash attention (unchanged from r7) ---------------
__global__ __launch_bounds__(256, 2) void attn_kernel(
    const unsigned short* __restrict__ Qb,   // [B,H,S,64]
    const unsigned short* __restrict__ Kb,   // [B,H,S,64]
    const unsigned short* __restrict__ Vt,   // [B,H,64,S]
    unsigned short* __restrict__ Oout)       // [B*S, 1024] token-major
{
    __shared__ unsigned short sK[128 * 64];
    __shared__ unsigned short sV[64 * 128];
    __shared__ unsigned short sP[4][32 * 128];

    const int tid = threadIdx.x, wid = tid >> 6, lane = tid & 63;
    const int fr = lane & 15, fg = lane >> 4;
    const int qt = blockIdx.x, bh = blockIdx.y;
    const int q0 = qt * 128;
    const size_t base = (size_t)bh * (S_LEN * DK);

    bf16x8 qf[2][2];
    #pragma unroll
    for (int mf = 0; mf < 2; ++mf)
        #pragma unroll
        for (int kf = 0; kf < 2; ++kf)
            qf[mf][kf] = *(const bf16x8*)(Qb + base +
                (size_t)(q0 + wid * 32 + mf * 16 + fr) * DK + kf * 32 + fg * 8);

    f32x4 oacc[2][4] = {};
    float m_run[2][4], l_run[2][4];
    #pragma unroll
    for (int mf = 0; mf < 2; ++mf)
        #pragma unroll
        for (int r = 0; r < 4; ++r) { m_run[mf][r] = NEG_BIG; l_run[mf][r] = 0.f; }

    const int t_lo = (qt == 0) ? 1 : 0;
    const int t_hi = (qt == (S_LEN / 128 - 1)) ? 1 : 2;

    for (int t = t_lo; t <= t_hi; ++t) {
        const int kt0 = q0 + (t - 1) * 128;
        __syncthreads();
        {
            const unsigned short* gK = Kb + base + (size_t)kt0 * DK;
            #pragma unroll
            for (int it = 0; it < 4; ++it) {
                const int chunk = wid * 4 + it;
                gload_lds16(gK + chunk * 512 + lane * 8, sK + chunk * 512);
            }
            const unsigned short* gV = Vt + base + kt0;
            #pragma unroll
            for (int it = 0; it < 4; ++it) {
                const int chunk = wid * 4 + it;
                gload_lds16(gV + (size_t)(chunk * 4 + fg) * S_LEN + fr * 8, sV + chunk * 512);
            }
        }
        __syncthreads();

        f32x4 sacc[2][8] = {};
        #pragma unroll
        for (int kf = 0; kf < 2; ++kf) {
            bf16x8 kfr[8];
            #pragma unroll
            for (int nf = 0; nf < 8; ++nf)
                kfr[nf] = *(const bf16x8*)(sK + (nf * 16 + fr) * 64 + kf * 32 + fg * 8);
            #pragma unroll
            for (int mf = 0; mf < 2; ++mf)
                #pragma unroll
                for (int nf = 0; nf < 8; ++nf)
                    sacc[mf][nf] = mfma16(qf[mf][kf], kfr[nf], sacc[mf][nf]);
        }

        const int dt = (t - 1) * 128;
        #pragma unroll
        for (int mf = 0; mf < 2; ++mf) {
            #pragma unroll
            for (int r = 0; r < 4; ++r) {
                const int row = wid * 32 + mf * 16 + fg * 4 + r;
                float mm = NEG_BIG;
                #pragma unroll
                for (int nf = 0; nf < 8; ++nf) {
                    const int col = nf * 16 + fr;
                    const int diff = dt + col - row;
                    float s = sacc[mf][nf][r] * QK_SCALE;
                    s = (diff >= -128 && diff < 128) ? s : NEG_BIG;
                    sacc[mf][nf][r] = s;
                    mm = fmaxf(mm, s);
                }
                #pragma unroll
                for (int d = 1; d < 16; d <<= 1) mm = fmaxf(mm, __shfl_xor(mm, d));
                const float mold = m_run[mf][r];
                const float mn = fmaxf(mold, mm);
                m_run[mf][r] = mn;
                const float alpha = __expf(mold - mn);
                float ps = 0.f;
                #pragma unroll
                for (int nf = 0; nf < 8; ++nf) {
                    const float p = __expf(sacc[mf][nf][r] - mn);
                    ps += p;
                    sP[wid][(mf * 16 + fg * 4 + r) * 128 + nf * 16 + fr] = f2bf(p);
                }
                #pragma unroll
                for (int d = 1; d < 16; d <<= 1) ps += __shfl_xor(ps, d);
                l_run[mf][r] = l_run[mf][r] * alpha + ps;
                #pragma unroll
                for (int nf = 0; nf < 4; ++nf)
                    oacc[mf][nf][r] = oacc[mf][nf][r] * alpha;
            }
        }

        #pragma unroll
        for (int kf = 0; kf < 4; ++kf) {
            bf16x8 pa[2], vb[4];
            #pragma unroll
            for (int mf = 0; mf < 2; ++mf)
                pa[mf] = *(const bf16x8*)(&sP[wid][(mf * 16 + fr) * 128 + kf * 32 + fg * 8]);
            #pragma unroll
            for (int nf = 0; nf < 4; ++nf)
                vb[nf] = *(const bf16x8*)(sV + (nf * 16 + fr) * 128 + kf * 32 + fg * 8);
            #pragma unroll
            for (int mf = 0; mf < 2; ++mf)
                #pragma unroll
                for (int nf = 0; nf < 4; ++nf)
                    oacc[mf][nf] = mfma16(pa[mf], vb[nf], oacc[mf][nf]);
        }
    }

    const int b = bh >> 4, h = bh & 15;
    #pragma unroll
    for (int mf = 0; mf < 2; ++mf) {
        #pragma unroll
        for (int r = 0; r < 4; ++r) {
            const float inv = 1.0f / l_run[mf][r];
            const int token = b * S_LEN + q0 + wid * 32 + mf * 16 + fg * 4 + r;
            #pragma unroll
            for (int nf = 0; nf < 4; ++nf) {
                const int feat = h * 64 + nf * 16 + fr;
                Oout[(size_t)token * DM + feat] = f2bf(oacc[mf][nf][r] * inv);
            }
        }
    }
}

// ---------------------------------------------------------------------------
extern "C" void kernel_launch(void* const* d_in, const int* in_sizes, int n_in,
                              void* d_out, int out_size, void* d_ws, size_t ws_size,
                              hipStream_t stream)
{
    (void)in_sizes; (void)n_in; (void)out_size; (void)ws_size;
    const float* q  = (const float*)d_in[0];
    const float* k  = (const float*)d_in[1];
    const float* v  = (const float*)d_in[2];
    const float* Wq = (const float*)d_in[3];
    const float* bq = (const float*)d_in[4];
    const float* Wk = (const float*)d_in[5];
    const float* bk = (const float*)d_in[6];
    const float* Wv = (const float*)d_in[7];
    const float* bv = (const float*)d_in[8];
    const float* Wo = (const float*)d_in[9];
    const float* bo = (const float*)d_in[10];

    char* ws = (char*)d_ws;
    const size_t MB = 1024 * 1024;
    unsigned short* Xq  = (unsigned short*)(ws + 0 * MB);   // 8 MiB, later reused as attn-out
    unsigned short* Xk  = (unsigned short*)(ws + 8 * MB);   // 8 MiB
    unsigned short* Xv  = (unsigned short*)(ws + 16 * MB);  // 8 MiB
    unsigned short* Qb  = (unsigned short*)(ws + 24 * MB);  // 8 MiB
    unsigned short* Kb  = (unsigned short*)(ws + 32 * MB);  // 8 MiB
    unsigned short* Vt  = (unsigned short*)(ws + 40 * MB);  // 8 MiB
    unsigned short* Wqb = (unsigned short*)(ws + 48 * MB);  // 2 MiB
    unsigned short* Wkb = (unsigned short*)(ws + 50 * MB);  // 2 MiB
    unsigned short* Wvb = (unsigned short*)(ws + 52 * MB);  // 2 MiB
    unsigned short* Wob = (unsigned short*)(ws + 54 * MB);  // 2 MiB
    unsigned short* AO  = Xq;  // attn output aliases Xq (free after Q-projection)

    CvtArgs ca;
    ca.src[0] = q;  ca.dst[0] = Xq;  ca.n8[0] = (NB * S_LEN * DM) / 8;
    ca.src[1] = k;  ca.dst[1] = Xk;  ca.n8[1] = (NB * S_LEN * DM) / 8;
    ca.src[2] = v;  ca.dst[2] = Xv;  ca.n8[2] = (NB * S_LEN * DM) / 8;
    ca.src[3] = Wq; ca.dst[3] = Wqb; ca.n8[3] = (DM * DM) / 8;
    ca.src[4] = Wk; ca.dst[4] = Wkb; ca.n8[4] = (DM * DM) / 8;
    ca.src[5] = Wv; ca.dst[5] = Wvb; ca.n8[5] = (DM * DM) / 8;
    ca.src[6] = Wo; ca.dst[6] = Wob; ca.n8[6] = (DM * DM) / 8;
    cvt_f32_bf16<<<dim3(1024, 7), 256, 0, stream>>>(ca);

    gemm_qkv<<<dim3(DM / 128, (NB * S_LEN) / 128, 3), 256, 0, stream>>>(
        Xq, Xk, Xv, Wqb, Wkb, Wvb, bq, bk, bv, Qb, Kb, Vt);

    attn_kernel<<<dim3(S_LEN / 128, NB * NH), 256, 0, stream>>>(Qb, Kb, Vt, AO);

    gemm_out<<<dim3(DM / 128, (NB * S_LEN) / 64), 256, 0, stream>>>(
        AO, Wob, bo, (float*)d_out);
}